// Round 10
// baseline (67.992 us; speedup 1.0000x reference)
//
#include <hip/hip_runtime.h>
#include <math.h>

#define HH 256
#define WW 256
#define BB 32
#define NW 8  // 256 rows = 8 x u32 words per column bitmask

// MEASUREMENT ROUND: rep-loops dilate each kernel past the 40us harness
// fills so rocprof top-5 shows per-kernel counters.  Bodies are idempotent;
// asm memory-clobber prevents iteration CSE; trailing barriers prevent
// WAR races between reps.  Outputs identical to R8.
#define REP_BM 16
#define REP_ST 4

// ---------------------------------------------------------------------------
// Kernel A: build column bitmasks.  P bit = (pred > 0.5), T bit = (target==1).
// ---------------------------------------------------------------------------
__global__ __launch_bounds__(256) void bitmask_kernel(
    const float* __restrict__ pred, const float* __restrict__ tgt,
    unsigned int* __restrict__ P, unsigned int* __restrict__ T) {
  const int b  = blockIdx.x >> 5;
  const int j  = (blockIdx.x >> 2) & 7;
  const int wq = blockIdx.x & 3;
  const int r    = threadIdx.x >> 6;
  const int lane = threadIdx.x & 63;
  const int col  = wq * 64 + lane;
  const int row0 = j * 32 + r * 8;

  __shared__ unsigned int sP[4][64], sT[4][64];

  for (int rep = 0; rep < REP_BM; ++rep) {
    const float* pin = pred + (size_t)b * (HH * WW) + row0 * WW + col;
    const float* tin = tgt  + (size_t)b * (HH * WW) + row0 * WW + col;
    unsigned int pb = 0, tb = 0;
#pragma unroll
    for (int i = 0; i < 8; ++i) {
      pb |= (pin[i * WW] > 0.5f ? 1u : 0u) << i;
      tb |= (tin[i * WW] == 1.0f ? 1u : 0u) << i;
    }

    sP[r][lane] = pb << (r * 8);
    sT[r][lane] = tb << (r * 8);
    __syncthreads();
    if (r == 0) {
      P[((size_t)b * NW + j) * WW + col] =
          sP[0][lane] | sP[1][lane] | sP[2][lane] | sP[3][lane];
      T[((size_t)b * NW + j) * WW + col] =
          sT[0][lane] | sT[1][lane] | sT[2][lane] | sT[3][lane];
    }
    __syncthreads();                    // WAR safety for next rep
    asm volatile("" ::: "memory");      // keep reps live
  }
}

// ---------------------------------------------------------------------------
// Kernel B (R8 FUSED coledt+minplus, 256 blocks x 512 thr), rep x4.
// ---------------------------------------------------------------------------
__global__ __launch_bounds__(512) void stripe_kernel(
    const unsigned int* __restrict__ P, const unsigned int* __restrict__ T,
    float* __restrict__ partial) {
  const int blk = blockIdx.x;          // b*8 + j
  const int b = blk >> 3;
  const int j = blk & 7;
  const int tid = threadIdx.x;

  __shared__ float sp[32][WW];
  __shared__ float st[32][WW];

  for (int rep = 0; rep < REP_ST; ++rep) {
    // ---- phase 1: column chains (one map per thread-half) ----
    {
      const int mp = tid >> 8;
      const int w  = tid & 255;
      const unsigned int* M = mp ? T : P;

      unsigned int Wd[NW];
#pragma unroll
      for (int jj = 0; jj < NW; ++jj)
        Wd[jj] = M[((size_t)b * NW + jj) * WW + w];

      unsigned int E[NW];
#pragma unroll
      for (int jj = 0; jj < NW - 1; ++jj)
        E[jj] = Wd[jj] ^ ((Wd[jj] >> 1) | (Wd[jj + 1] << 31));
      E[NW - 1] = (Wd[NW - 1] ^ (Wd[NW - 1] >> 1)) & 0x7FFFFFFFu;

      unsigned int EJ = 0, EJm1 = 0, WJ = 0;
#pragma unroll
      for (int jj = 0; jj < NW; ++jj) {
        if (j == jj) { EJ = E[jj]; WJ = Wd[jj]; }
        if (j - 1 == jj) EJm1 = E[jj];
      }

      int emax = -100000;
#pragma unroll
      for (int jj = 0; jj < NW - 1; ++jj)
        if (jj < j && E[jj]) emax = 32 * jj + 31 - __builtin_clz(E[jj]);
      int D = (j * 32 - 1) - emax;
      if (D > 513) D = 513;

      int emin = 100000;
#pragma unroll
      for (int jj = NW - 1; jj >= 1; --jj)
        if (jj > j && E[jj]) emin = 32 * jj + __builtin_ctz(E[jj]);
      int U = (emin + 1) - (j * 32 + 32);
      if (U > 513) U = 513;

      const unsigned int EQ = (EJ << 1) | (j ? (EJm1 >> 31) : 0u);

      unsigned int dn[16];
#pragma unroll
      for (int i = 0; i < 32; ++i) {
        D = ((EQ >> i) & 1u) ? 1 : (D + 1);
        if (i & 1) dn[i >> 1] |= (unsigned int)D << 16;
        else       dn[i >> 1] = (unsigned int)D;
      }

#pragma unroll
      for (int i = 31; i >= 0; --i) {
        U = ((EJ >> i) & 1u) ? 1 : (U + 1);
        int dnv = (int)((dn[i >> 1] >> ((i & 1) * 16)) & 0xFFFFu);
        int g = min(min(dnv, U), 512);
        float g2 = (float)(g * g);
        float v = ((WJ >> i) & 1u) ? -g2 : g2;
        if (mp == 0) sp[i][w] = v;
        else         st[i][w] = v;
      }
    }
    __syncthreads();

    // ---- phase 2: min-plus, 4 rows per wave ----
    const int wv = tid >> 6;
    const int lane = tid & 63;
    float acc = 0.f;

    for (int rr = 0; rr < 4; ++rr) {
      const int r = wv * 4 + rr;
      float m[4][4];
#pragma unroll
      for (int c = 0; c < 4; ++c) {
        float vp = sp[r][lane + 64 * c];
        float vt = st[r][lane + 64 * c];
        m[c][0] = fmaxf(vp, 0.f); m[c][1] = fmaxf(-vp, 0.f);
        m[c][2] = fmaxf(vt, 0.f); m[c][3] = fmaxf(-vt, 0.f);
      }

      for (int k = 1; k < WW; ++k) {
        const float c2 = (float)(k * k);
        float mx = 0.f;
#pragma unroll
        for (int c = 0; c < 4; ++c)
          mx = fmaxf(mx, fmaxf(fmaxf(m[c][0], m[c][1]),
                               fmaxf(m[c][2], m[c][3])));
        if (c2 >= mx) break;
#pragma unroll
        for (int c = 0; c < 4; ++c) {
          const int y = lane + 64 * c;
          const int lo = y - k;
          if (lo >= 0) {
            float vp = sp[r][lo], vt = st[r][lo];
            m[c][0] = fminf(m[c][0], fmaxf(vp, 0.f) + c2);
            m[c][1] = fminf(m[c][1], fmaxf(-vp, 0.f) + c2);
            m[c][2] = fminf(m[c][2], fmaxf(vt, 0.f) + c2);
            m[c][3] = fminf(m[c][3], fmaxf(-vt, 0.f) + c2);
          }
          const int hi = y + k;
          if (hi < WW) {
            float vp = sp[r][hi], vt = st[r][hi];
            m[c][0] = fminf(m[c][0], fmaxf(vp, 0.f) + c2);
            m[c][1] = fminf(m[c][1], fmaxf(-vp, 0.f) + c2);
            m[c][2] = fminf(m[c][2], fmaxf(vt, 0.f) + c2);
            m[c][3] = fminf(m[c][3], fmaxf(-vt, 0.f) + c2);
          }
        }
      }

      float val = 0.f;
#pragma unroll
      for (int c = 0; c < 4; ++c) {
        float pd = sqrtf(m[c][0]) + sqrtf(m[c][1]);
        float td = sqrtf(m[c][2]) + sqrtf(m[c][3]);
        float diff = pd - td;
        val += diff * diff * td * td;
      }
      for (int off = 32; off > 0; off >>= 1) val += __shfl_down(val, off);
      acc += val;
    }

    if (lane == 0) partial[blk * 8 + wv] = acc;
    __syncthreads();                    // WAR safety for next rep
    asm volatile("" ::: "memory");      // keep reps live
  }
}

// ---------------------------------------------------------------------------
// Kernel C: reduce 2048 partials in double, write mean.
// ---------------------------------------------------------------------------
__global__ __launch_bounds__(256) void finalize_kernel(
    const float* __restrict__ partial, float* __restrict__ out) {
  __shared__ double sd[256];
  double sum = 0.0;
  for (int i = threadIdx.x; i < 2048; i += 256) sum += (double)partial[i];
  sd[threadIdx.x] = sum;
  __syncthreads();
  for (int stride = 128; stride > 0; stride >>= 1) {
    if (threadIdx.x < stride) sd[threadIdx.x] += sd[threadIdx.x + stride];
    __syncthreads();
  }
  if (threadIdx.x == 0)
    out[0] = (float)(sd[0] / (double)((size_t)BB * HH * WW));
}

extern "C" void kernel_launch(void* const* d_in, const int* in_sizes, int n_in,
                              void* d_out, int out_size, void* d_ws, size_t ws_size,
                              hipStream_t stream) {
  const float* pred = (const float*)d_in[0];
  const float* tgt  = (const float*)d_in[1];
  float* out = (float*)d_out;

  unsigned int* P = (unsigned int*)d_ws;
  unsigned int* T = P + (size_t)BB * NW * WW;
  float* partial = (float*)(T + (size_t)BB * NW * WW);

  hipLaunchKernelGGL(bitmask_kernel, dim3(BB * NW * 4), dim3(256), 0, stream,
                     pred, tgt, P, T);
  hipLaunchKernelGGL(stripe_kernel, dim3(BB * NW), dim3(512), 0, stream,
                     P, T, partial);
  hipLaunchKernelGGL(finalize_kernel, dim3(1), dim3(256), 0, stream,
                     partial, out);
}

// Round 11
// 30.326 us; speedup vs baseline: 2.2420x; 2.2420x over previous
//
#include <hip/hip_runtime.h>
#include <math.h>

#define HH 256
#define WW 256
#define BB 32
#define NW 8  // 256 rows = 8 x u32 words per column bitmask

// ---------------------------------------------------------------------------
// Kernel A: build column bitmasks.  P bit = (pred > 0.5), T bit = (target==1).
// Grid: BB*NW*4 = 1024 blocks (measured ~0.5-1us total).
// ---------------------------------------------------------------------------
__global__ __launch_bounds__(256) void bitmask_kernel(
    const float* __restrict__ pred, const float* __restrict__ tgt,
    unsigned int* __restrict__ P, unsigned int* __restrict__ T) {
  const int b  = blockIdx.x >> 5;
  const int j  = (blockIdx.x >> 2) & 7;
  const int wq = blockIdx.x & 3;
  const int r    = threadIdx.x >> 6;
  const int lane = threadIdx.x & 63;
  const int col  = wq * 64 + lane;
  const int row0 = j * 32 + r * 8;

  const float* pin = pred + (size_t)b * (HH * WW) + row0 * WW + col;
  const float* tin = tgt  + (size_t)b * (HH * WW) + row0 * WW + col;
  unsigned int pb = 0, tb = 0;
#pragma unroll
  for (int i = 0; i < 8; ++i) {
    pb |= (pin[i * WW] > 0.5f ? 1u : 0u) << i;
    tb |= (tin[i * WW] == 1.0f ? 1u : 0u) << i;
  }

  __shared__ unsigned int sP[4][64], sT[4][64];
  sP[r][lane] = pb << (r * 8);
  sT[r][lane] = tb << (r * 8);
  __syncthreads();
  if (r == 0) {
    P[((size_t)b * NW + j) * WW + col] =
        sP[0][lane] | sP[1][lane] | sP[2][lane] | sP[3][lane];
    T[((size_t)b * NW + j) * WW + col] =
        sT[0][lane] | sT[1][lane] | sT[2][lane] | sT[3][lane];
  }
}

// ---------------------------------------------------------------------------
// Kernel B (stripe8x): 1024 blocks x 256 threads, 8-row stripe, 16 KB LDS
// -> 4 blocks/CU = 16 waves/CU (2x R8's concurrency).
//   Phase 1: each thread (column w) runs BOTH maps' edge-mask chains for the
//     stripe's 8 rows (sub-word seeds, js block-uniform -> scalar shifts);
//     stores float2 {vP, vT}, v = own ? -g^2 : +g^2.
//   Phase 2: XOR-FOLD min-plus: per pixel only the distance to the
//     DIFFERING class is nonzero, so each lane tracks 2 mins (not 4):
//     needed(w) = fmax(asfloat(asint(v)^ownsign), 0).  64 VALU + 8 b64
//     LDS reads per k-iter (R8: ~110 + 16 b32).  Exact early exit kept.
// ---------------------------------------------------------------------------
__global__ __launch_bounds__(256) void stripe8x_kernel(
    const unsigned int* __restrict__ P, const unsigned int* __restrict__ T,
    float* __restrict__ partial) {
  const int blk = blockIdx.x;          // b*32 + js
  const int b  = blk >> 5;
  const int js = blk & 31;
  const int base = js * 8;             // first row of stripe
  const int wq0 = base >> 5, sub = base & 31;   // block-uniform, sub in {0,8,16,24}
  const int tid = threadIdx.x;

  __shared__ float2 sv[8][WW];         // {pred, target} signed g^2

  // ---- phase 1: both maps per thread ----
  {
    const int w = tid;
    unsigned int Pw[NW], Tw[NW];
#pragma unroll
    for (int jj = 0; jj < NW; ++jj) {
      Pw[jj] = P[((size_t)b * NW + jj) * WW + w];
      Tw[jj] = T[((size_t)b * NW + jj) * WW + w];
    }

    const unsigned int submask = sub ? ((1u << sub) - 1u) : 0u;
    const int r8 = base + 8;
    const int wr = r8 >> 5;
    const unsigned int upmask =
        (r8 & 31) ? ~((1u << (r8 & 31)) - 1u) : 0xFFFFFFFFu;

    float vp[8], vt[8];                // static idx after unroll

#define RUN_CHAIN(Wd, vout)                                                  \
    {                                                                        \
      unsigned int E[NW];                                                    \
      _Pragma("unroll")                                                      \
      for (int jj = 0; jj < NW - 1; ++jj)                                    \
        E[jj] = Wd[jj] ^ ((Wd[jj] >> 1) | (Wd[jj + 1] << 31));               \
      E[NW - 1] = (Wd[NW - 1] ^ (Wd[NW - 1] >> 1)) & 0x7FFFFFFFu;            \
      unsigned int Ew = 0, Ewm1 = 0, Ww = 0;                                 \
      _Pragma("unroll")                                                      \
      for (int jj = 0; jj < NW; ++jj) {                                      \
        if (jj == wq0) { Ew = E[jj]; Ww = Wd[jj]; }                          \
        if (jj == wq0 - 1) Ewm1 = E[jj];                                     \
      }                                                                      \
      const unsigned int EU8 = (Ew >> sub) & 0xFFu;                          \
      const unsigned int EQ8 =                                               \
          sub ? ((Ew >> (sub - 1)) & 0xFFu)                                  \
              : (((Ew << 1) | (wq0 ? (Ewm1 >> 31) : 0u)) & 0xFFu);           \
      const unsigned int W8 = (Ww >> sub) & 0xFFu;                           \
      int emax = -100000;                                                    \
      _Pragma("unroll")                                                      \
      for (int jj = 0; jj < NW; ++jj) {                                      \
        unsigned int a = (jj < wq0) ? E[jj]                                  \
                         : ((jj == wq0) ? (E[jj] & submask) : 0u);           \
        if (a) emax = 32 * jj + 31 - __builtin_clz(a);                       \
      }                                                                      \
      int D = (base - 1) - emax;                                             \
      if (D > 513) D = 513;                                                  \
      int emin = 100000;                                                     \
      _Pragma("unroll")                                                      \
      for (int jj = NW - 1; jj >= 0; --jj) {                                 \
        unsigned int a = (jj > wr) ? E[jj]                                   \
                         : ((jj == wr) ? (E[jj] & upmask) : 0u);             \
        if (a) emin = 32 * jj + __builtin_ctz(a);                            \
      }                                                                      \
      int U = (emin + 1) - r8;                                               \
      if (U > 513) U = 513;                                                  \
      int dn[8];                                                             \
      _Pragma("unroll")                                                      \
      for (int i = 0; i < 8; ++i) {                                          \
        D = ((EQ8 >> i) & 1u) ? 1 : (D + 1);                                 \
        dn[i] = D;                                                           \
      }                                                                      \
      _Pragma("unroll")                                                      \
      for (int i = 7; i >= 0; --i) {                                         \
        U = ((EU8 >> i) & 1u) ? 1 : (U + 1);                                 \
        int g = min(min(dn[i], U), 512);                                     \
        float g2 = (float)(g * g);                                           \
        vout[i] = ((W8 >> i) & 1u) ? -g2 : g2;                               \
      }                                                                      \
    }

    RUN_CHAIN(Pw, vp)
    RUN_CHAIN(Tw, vt)
#undef RUN_CHAIN

#pragma unroll
    for (int i = 0; i < 8; ++i) sv[i][w] = make_float2(vp[i], vt[i]);
  }
  __syncthreads();

  // ---- phase 2: 2 rows per wave, XOR-fold min-plus ----
  const int wv = tid >> 6;
  const int lane = tid & 63;

  for (int rr = 0; rr < 2; ++rr) {
    const int r = wv * 2 + rr;

    float mp[4], mt[4];                // per owned column, static idx
    unsigned int sgp[4], sgt[4];       // own-sign masks (0 or 0x80000000)
#pragma unroll
    for (int c = 0; c < 4; ++c) {
      float2 v = sv[r][lane + 64 * c];
      sgp[c] = __float_as_uint(v.x) & 0x80000000u;
      sgt[c] = __float_as_uint(v.y) & 0x80000000u;
      mp[c] = fabsf(v.x);              // self candidate: always +g^2
      mt[c] = fabsf(v.y);
    }

    for (int k = 1; k < WW; ++k) {
      const float c2 = (float)(k * k);
      float mx = fmaxf(fmaxf(fmaxf(mp[0], mp[1]), fmaxf(mp[2], mp[3])),
                       fmaxf(fmaxf(mt[0], mt[1]), fmaxf(mt[2], mt[3])));
      if (c2 >= mx) break;             // exact: remaining candidates >= k^2
#pragma unroll
      for (int c = 0; c < 4; ++c) {
        const int y = lane + 64 * c;
        const int lo = y - k;
        if (lo >= 0) {
          float2 v = sv[r][lo];
          mp[c] = fminf(mp[c],
              fmaxf(__uint_as_float(__float_as_uint(v.x) ^ sgp[c]), 0.f) + c2);
          mt[c] = fminf(mt[c],
              fmaxf(__uint_as_float(__float_as_uint(v.y) ^ sgt[c]), 0.f) + c2);
        }
        const int hi = y + k;
        if (hi < WW) {
          float2 v = sv[r][hi];
          mp[c] = fminf(mp[c],
              fmaxf(__uint_as_float(__float_as_uint(v.x) ^ sgp[c]), 0.f) + c2);
          mt[c] = fminf(mt[c],
              fmaxf(__uint_as_float(__float_as_uint(v.y) ^ sgt[c]), 0.f) + c2);
        }
      }
    }

    float val = 0.f;
#pragma unroll
    for (int c = 0; c < 4; ++c) {
      float pd = sqrtf(mp[c]);         // pred_dist (other term is 0)
      float td = sqrtf(mt[c]);         // target_dist
      float diff = pd - td;
      val += diff * diff * td * td;    // (pd-td)^2 * td^ALPHA, ALPHA=2
    }
    for (int off = 32; off > 0; off >>= 1) val += __shfl_down(val, off);
    if (lane == 0) partial[blk * 8 + r] = val;   // 8192 partials
  }
}

// ---------------------------------------------------------------------------
// Kernel C: reduce 8192 partials in double, write mean.
// ---------------------------------------------------------------------------
__global__ __launch_bounds__(256) void finalize_kernel(
    const float* __restrict__ partial, float* __restrict__ out) {
  __shared__ double sd[256];
  double sum = 0.0;
  for (int i = threadIdx.x; i < BB * HH; i += 256) sum += (double)partial[i];
  sd[threadIdx.x] = sum;
  __syncthreads();
  for (int stride = 128; stride > 0; stride >>= 1) {
    if (threadIdx.x < stride) sd[threadIdx.x] += sd[threadIdx.x + stride];
    __syncthreads();
  }
  if (threadIdx.x == 0)
    out[0] = (float)(sd[0] / (double)((size_t)BB * HH * WW));
}

extern "C" void kernel_launch(void* const* d_in, const int* in_sizes, int n_in,
                              void* d_out, int out_size, void* d_ws, size_t ws_size,
                              hipStream_t stream) {
  const float* pred = (const float*)d_in[0];
  const float* tgt  = (const float*)d_in[1];
  float* out = (float*)d_out;

  // ws: P (256 KB), T (256 KB), partial (32 KB)
  unsigned int* P = (unsigned int*)d_ws;
  unsigned int* T = P + (size_t)BB * NW * WW;
  float* partial = (float*)(T + (size_t)BB * NW * WW);

  hipLaunchKernelGGL(bitmask_kernel, dim3(BB * NW * 4), dim3(256), 0, stream,
                     pred, tgt, P, T);
  hipLaunchKernelGGL(stripe8x_kernel, dim3(BB * 32), dim3(256), 0, stream,
                     P, T, partial);
  hipLaunchKernelGGL(finalize_kernel, dim3(1), dim3(256), 0, stream,
                     partial, out);
}

// Round 12
// 25.742 us; speedup vs baseline: 2.6413x; 1.1781x over previous
//
#include <hip/hip_runtime.h>
#include <math.h>

#define HH 256
#define WW 256
#define BB 32
#define NW 8  // 256 rows = 8 x u32 words per column bitmask

// ---------------------------------------------------------------------------
// Kernel A: build column bitmasks.  P bit = (pred > 0.5), T bit = (target==1).
// Also zeroes the ticket counter for kernel B (stream-ordered before it).
// Grid: BB*NW*4 = 1024 blocks (measured ~0.2us).
// ---------------------------------------------------------------------------
__global__ __launch_bounds__(256) void bitmask_kernel(
    const float* __restrict__ pred, const float* __restrict__ tgt,
    unsigned int* __restrict__ P, unsigned int* __restrict__ T,
    unsigned int* __restrict__ cnt) {
  if (blockIdx.x == 0 && threadIdx.x == 0)
    __hip_atomic_store(cnt, 0u, __ATOMIC_RELAXED, __HIP_MEMORY_SCOPE_AGENT);

  const int b  = blockIdx.x >> 5;
  const int j  = (blockIdx.x >> 2) & 7;
  const int wq = blockIdx.x & 3;
  const int r    = threadIdx.x >> 6;
  const int lane = threadIdx.x & 63;
  const int col  = wq * 64 + lane;
  const int row0 = j * 32 + r * 8;

  const float* pin = pred + (size_t)b * (HH * WW) + row0 * WW + col;
  const float* tin = tgt  + (size_t)b * (HH * WW) + row0 * WW + col;
  unsigned int pb = 0, tb = 0;
#pragma unroll
  for (int i = 0; i < 8; ++i) {
    pb |= (pin[i * WW] > 0.5f ? 1u : 0u) << i;
    tb |= (tin[i * WW] == 1.0f ? 1u : 0u) << i;
  }

  __shared__ unsigned int sP[4][64], sT[4][64];
  sP[r][lane] = pb << (r * 8);
  sT[r][lane] = tb << (r * 8);
  __syncthreads();
  if (r == 0) {
    P[((size_t)b * NW + j) * WW + col] =
        sP[0][lane] | sP[1][lane] | sP[2][lane] | sP[3][lane];
    T[((size_t)b * NW + j) * WW + col] =
        sT[0][lane] | sT[1][lane] | sT[2][lane] | sT[3][lane];
  }
}

// ---------------------------------------------------------------------------
// Kernel B (FUSED, LAST-BLOCK-FINALIZE): 256 blocks x 512 thr, 32-row stripe
// (minimum phase-1 work: each column scanned once per map).
//   Phase 1 (R8-verified chains): threads 0-255 pred / 256-511 target write
//     sign-encoded g^2 (own? -g^2:+g^2) into interleaved float2 LDS.
//   Phase 2: XOR-fold min-plus (2 tracked mins per column, not 4):
//     needed(w) = fmax(asfloat(asint(v)^ownsign), 0); 8 b64 LDS reads/iter.
//     Exact early exit.  One shuffle reduce per wave (not per row).
//   Tail: agent-scope atomic partial stores + ticket; last block atomic-loads
//     all 2048 partials (fresh past per-XCD L2s) and writes the double mean.
// ---------------------------------------------------------------------------
__global__ __launch_bounds__(512) void stripe_kernel(
    const unsigned int* __restrict__ P, const unsigned int* __restrict__ T,
    float* __restrict__ partial, unsigned int* __restrict__ cnt,
    float* __restrict__ out) {
  const int blk = blockIdx.x;          // b*8 + j
  const int b = blk >> 3;
  const int j = blk & 7;
  const int tid = threadIdx.x;

  __shared__ float2 sv[32][WW];        // 64 KB: {pred, target} signed g^2
  __shared__ double sd[512];
  __shared__ unsigned int isLast;

  // ---- phase 1: column chains (one map per thread-half) ----
  {
    const int mp = tid >> 8;           // 0: pred, 1: target
    const int w  = tid & 255;
    const unsigned int* M = mp ? T : P;

    unsigned int Wd[NW];
#pragma unroll
    for (int jj = 0; jj < NW; ++jj)
      Wd[jj] = M[((size_t)b * NW + jj) * WW + w];

    unsigned int E[NW];
#pragma unroll
    for (int jj = 0; jj < NW - 1; ++jj)
      E[jj] = Wd[jj] ^ ((Wd[jj] >> 1) | (Wd[jj + 1] << 31));
    E[NW - 1] = (Wd[NW - 1] ^ (Wd[NW - 1] >> 1)) & 0x7FFFFFFFu;

    unsigned int EJ = 0, EJm1 = 0, WJ = 0;
#pragma unroll
    for (int jj = 0; jj < NW; ++jj) {
      if (j == jj) { EJ = E[jj]; WJ = Wd[jj]; }
      if (j - 1 == jj) EJm1 = E[jj];
    }

    int emax = -100000;
#pragma unroll
    for (int jj = 0; jj < NW - 1; ++jj)
      if (jj < j && E[jj]) emax = 32 * jj + 31 - __builtin_clz(E[jj]);
    int D = (j * 32 - 1) - emax;
    if (D > 513) D = 513;

    int emin = 100000;
#pragma unroll
    for (int jj = NW - 1; jj >= 1; --jj)
      if (jj > j && E[jj]) emin = 32 * jj + __builtin_ctz(E[jj]);
    int U = (emin + 1) - (j * 32 + 32);
    if (U > 513) U = 513;

    const unsigned int EQ = (EJ << 1) | (j ? (EJm1 >> 31) : 0u);

    unsigned int dn[16];
#pragma unroll
    for (int i = 0; i < 32; ++i) {
      D = ((EQ >> i) & 1u) ? 1 : (D + 1);
      if (i & 1) dn[i >> 1] |= (unsigned int)D << 16;
      else       dn[i >> 1] = (unsigned int)D;
    }

#pragma unroll
    for (int i = 31; i >= 0; --i) {
      U = ((EJ >> i) & 1u) ? 1 : (U + 1);
      int dnv = (int)((dn[i >> 1] >> ((i & 1) * 16)) & 0xFFFFu);
      int g = min(min(dnv, U), 512);   // cap = H+W (exact, incl. empty cols)
      float g2 = (float)(g * g);
      float v = ((WJ >> i) & 1u) ? -g2 : g2;
      *(((float*)&sv[i][w]) + mp) = v; // mp=0 -> .x, mp=1 -> .y
    }
  }
  __syncthreads();

  // ---- phase 2: 4 rows per wave, XOR-fold min-plus ----
  const int wv = tid >> 6;
  const int lane = tid & 63;
  float acc = 0.f;

  for (int rr = 0; rr < 4; ++rr) {
    const int r = wv * 4 + rr;

    float m1[4], m2[4];                // tracked (differing-class) mins
    unsigned int sg1[4], sg2[4];       // own-sign masks (0 or 0x80000000)
#pragma unroll
    for (int c = 0; c < 4; ++c) {
      float2 v = sv[r][lane + 64 * c];
      sg1[c] = __float_as_uint(v.x) & 0x80000000u;
      sg2[c] = __float_as_uint(v.y) & 0x80000000u;
      m1[c] = fabsf(v.x);              // self candidate (offset 0)
      m2[c] = fabsf(v.y);
    }

    for (int k = 1; k < WW; ++k) {
      const float c2 = (float)(k * k);
      float mx = fmaxf(fmaxf(fmaxf(m1[0], m1[1]), fmaxf(m1[2], m1[3])),
                       fmaxf(fmaxf(m2[0], m2[1]), fmaxf(m2[2], m2[3])));
      if (c2 >= mx) break;             // exact: remaining candidates >= k^2
#pragma unroll
      for (int c = 0; c < 4; ++c) {
        const int y = lane + 64 * c;
        const int lo = y - k;
        if (lo >= 0) {
          float2 v = sv[r][lo];
          m1[c] = fminf(m1[c],
              fmaxf(__uint_as_float(__float_as_uint(v.x) ^ sg1[c]), 0.f) + c2);
          m2[c] = fminf(m2[c],
              fmaxf(__uint_as_float(__float_as_uint(v.y) ^ sg2[c]), 0.f) + c2);
        }
        const int hi = y + k;
        if (hi < WW) {
          float2 v = sv[r][hi];
          m1[c] = fminf(m1[c],
              fmaxf(__uint_as_float(__float_as_uint(v.x) ^ sg1[c]), 0.f) + c2);
          m2[c] = fminf(m2[c],
              fmaxf(__uint_as_float(__float_as_uint(v.y) ^ sg2[c]), 0.f) + c2);
        }
      }
    }

#pragma unroll
    for (int c = 0; c < 4; ++c) {
      float pd = sqrtf(m1[c]);         // pred_dist (own-class term is 0)
      float td = sqrtf(m2[c]);         // target_dist
      float diff = pd - td;
      acc += diff * diff * (td * td);  // matches reference rounding
    }
  }

  for (int off = 32; off > 0; off >>= 1) acc += __shfl_down(acc, off);
  if (lane == 0)
    __hip_atomic_store(&partial[blk * 8 + wv], acc, __ATOMIC_RELAXED,
                       __HIP_MEMORY_SCOPE_AGENT);

  // ---- ticket: last block reduces all 2048 partials, writes mean ----
  __syncthreads();
  if (tid == 0) {
    unsigned int old = __hip_atomic_fetch_add(cnt, 1u, __ATOMIC_ACQ_REL,
                                              __HIP_MEMORY_SCOPE_AGENT);
    isLast = (old == (unsigned int)(BB * NW - 1)) ? 1u : 0u;
  }
  __syncthreads();
  if (isLast) {
    double s = 0.0;
    for (int i = tid; i < BB * NW * 8; i += 512)
      s += (double)__hip_atomic_load(&partial[i], __ATOMIC_RELAXED,
                                     __HIP_MEMORY_SCOPE_AGENT);
    sd[tid] = s;
    __syncthreads();
    for (int st = 256; st > 0; st >>= 1) {
      if (tid < st) sd[tid] += sd[tid + st];
      __syncthreads();
    }
    if (tid == 0)
      out[0] = (float)(sd[0] / (double)((size_t)BB * HH * WW));
  }
}

extern "C" void kernel_launch(void* const* d_in, const int* in_sizes, int n_in,
                              void* d_out, int out_size, void* d_ws, size_t ws_size,
                              hipStream_t stream) {
  const float* pred = (const float*)d_in[0];
  const float* tgt  = (const float*)d_in[1];
  float* out = (float*)d_out;

  // ws: P (256 KB), T (256 KB), partial (8 KB), cnt (4 B)
  unsigned int* P = (unsigned int*)d_ws;
  unsigned int* T = P + (size_t)BB * NW * WW;
  float* partial = (float*)(T + (size_t)BB * NW * WW);
  unsigned int* cnt = (unsigned int*)(partial + BB * NW * 8);

  hipLaunchKernelGGL(bitmask_kernel, dim3(BB * NW * 4), dim3(256), 0, stream,
                     pred, tgt, P, T, cnt);
  hipLaunchKernelGGL(stripe_kernel, dim3(BB * NW), dim3(512), 0, stream,
                     P, T, partial, cnt, out);
}